// Round 5
// baseline (365.607 us; speedup 1.0000x reference)
//
#include <hip/hip_runtime.h>
#include <math.h>

// ---------------- degree / norm ----------------

__global__ void deg_kernel(const int* __restrict__ col, int* __restrict__ deg, int E) {
    int e = blockIdx.x * blockDim.x + threadIdx.x;
    if (e < E) atomicAdd(&deg[col[e]], 1);
}

__global__ void dinv_kernel(const int* __restrict__ deg, float* __restrict__ dinv, int n) {
    int i = blockIdx.x * blockDim.x + threadIdx.x;
    if (i < n) dinv[i] = 1.0f / sqrtf((float)(deg[i] + 1));  // +1 self loop
}

// ---------------- 3-phase scan: deg -> rowptr/cursor ----------------
__global__ void scan_phase1(const int* __restrict__ deg, int* __restrict__ bsum, int n) {
    __shared__ int red[256];
    int tid = threadIdx.x;
    int base = blockIdx.x * 1024 + tid * 4;
    int s = 0;
    if (base + 3 < n) { int4 v = *(const int4*)&deg[base]; s = v.x + v.y + v.z + v.w; }
    else { for (int i = 0; i < 4; ++i) if (base + i < n) s += deg[base + i]; }
    red[tid] = s; __syncthreads();
    for (int off = 128; off > 0; off >>= 1) { if (tid < off) red[tid] += red[tid + off]; __syncthreads(); }
    if (tid == 0) bsum[blockIdx.x] = red[0];
}

__global__ void scan_phase2(const int* __restrict__ bsum, int* __restrict__ bpre,
                            int nb, int* __restrict__ rowptr, int n, int E) {
    int tid = threadIdx.x;  // 64 threads
    int sv = (tid < nb) ? bsum[tid] : 0;
    int v = sv;
    for (int off = 1; off < 64; off <<= 1) {
        int w = __shfl_up(v, off);
        if (tid >= off) v += w;
    }
    if (tid < nb) bpre[tid] = v - sv;   // exclusive
    if (tid == 0) rowptr[n] = E;
}

__global__ void scan_phase3(const int* __restrict__ deg, const int* __restrict__ bpre,
                            int* __restrict__ rowptr, int* __restrict__ cursor, int n) {
    __shared__ int tsum[256];
    int tid = threadIdx.x;
    int base = blockIdx.x * 1024 + tid * 4;
    int d[4] = {0, 0, 0, 0};
    if (base + 3 < n) { int4 v = *(const int4*)&deg[base]; d[0] = v.x; d[1] = v.y; d[2] = v.z; d[3] = v.w; }
    else { for (int i = 0; i < 4; ++i) if (base + i < n) d[i] = deg[base + i]; }
    int s = d[0] + d[1] + d[2] + d[3];
    tsum[tid] = s; __syncthreads();
    for (int off = 1; off < 256; off <<= 1) {
        int v = tsum[tid];
        int w = (tid >= off) ? tsum[tid - off] : 0;
        __syncthreads();
        tsum[tid] = v + w;
        __syncthreads();
    }
    int pre = bpre[blockIdx.x] + tsum[tid] - s;
    for (int i = 0; i < 4; ++i) {
        int idx = base + i;
        if (idx < n) { rowptr[idx] = pre; cursor[idx] = pre; pre += d[i]; }
    }
}

__global__ void fill_kernel(const int* __restrict__ row, const int* __restrict__ col,
                            int* __restrict__ cursor, int* __restrict__ csrc, int E) {
    int e = blockIdx.x * blockDim.x + threadIdx.x;
    if (e < E) {
        int c = col[e];
        int slot = atomicAdd(&cursor[c], 1);
        csrc[slot] = row[e];
    }
}

// ---------------- CSR gather aggregation + finalize ----------------
template<int F, bool OV>
__global__ void agg_finalize(const int* __restrict__ rowptr, const int* __restrict__ csrc,
                             const float* __restrict__ hs, const float* __restrict__ dinv,
                             const float* __restrict__ b, float* __restrict__ out,
                             int n, int ostride, int col0) {
    constexpr int L = F / 4;                 // lanes per node
    int tid = blockIdx.x * blockDim.x + threadIdx.x;
    int node = tid / L, lane = tid % L;
    if (node >= n) return;
    int f0 = lane * 4;
    int beg = rowptr[node], end = rowptr[node + 1];
    float4 sum = make_float4(0.f, 0.f, 0.f, 0.f);
    for (int j = beg; j < end; ++j) {
        int s = csrc[j];                     // uniform across the L-lane group
        float4 v = *(const float4*)&hs[(size_t)s * F + f0];
        sum.x += v.x; sum.y += v.y; sum.z += v.z; sum.w += v.w;
    }
    float4 self = *(const float4*)&hs[(size_t)node * F + f0];
    float di = dinv[node];
    float r0 = fmaxf(di * (sum.x + self.x) + b[f0 + 0], 0.f);
    float r1 = fmaxf(di * (sum.y + self.y) + b[f0 + 1], 0.f);
    float r2 = fmaxf(di * (sum.z + self.z) + b[f0 + 2], 0.f);
    float r3 = fmaxf(di * (sum.w + self.w) + b[f0 + 3], 0.f);
    float* op = &out[(size_t)node * ostride + col0 + f0];
    if (OV) {
        *(float4*)op = make_float4(r0, r1, r2, r3);
    } else {
        op[0] = r0; op[1] = r1; op[2] = r2; op[3] = r3;
    }
}

// ---------------- GCN dense: out[r,c] = dinv[r] * sum_k x[r,k]*W[k,c] ----------------
template<int K, int OC>
__global__ __launch_bounds__(256) void gemm_gcn(
    const float* __restrict__ x, const float* __restrict__ W,
    const float* __restrict__ dinv, float* __restrict__ outp, int n) {
    constexpr int CG = OC / 8;        // col groups
    constexpr int RG = 256 / CG;      // row groups
    constexpr int ROWS = 64 / RG;     // rows per thread
    __shared__ float xL[64][K + 4];

    const int tid = threadIdx.x;
    const int cg = tid % CG, rg = tid / CG;
    const int c0 = cg * 8, r0 = rg * ROWS;
    const int row0 = blockIdx.x * 64;

#pragma unroll
    for (int i = 0; i < K / 16; ++i) {
        int e = tid + i * 256;
        int r = e / (K / 4), q = e % (K / 4);
        float4 v = make_float4(0.f, 0.f, 0.f, 0.f);
        if (row0 + r < n) v = *(const float4*)&x[(size_t)(row0 + r) * K + q * 4];
        *(float4*)&xL[r][q * 4] = v;
    }
    __syncthreads();

    float acc[ROWS][8];
#pragma unroll
    for (int r = 0; r < ROWS; ++r)
#pragma unroll
        for (int c = 0; c < 8; ++c) acc[r][c] = 0.f;

#pragma unroll 8
    for (int k = 0; k < K; ++k) {
        float4 w0 = *(const float4*)&W[(size_t)k * OC + c0];
        float4 w1 = *(const float4*)&W[(size_t)k * OC + c0 + 4];
        float wv[8] = {w0.x, w0.y, w0.z, w0.w, w1.x, w1.y, w1.z, w1.w};
        float xv[ROWS];
#pragma unroll
        for (int r = 0; r < ROWS; ++r) xv[r] = xL[r0 + r][k];
#pragma unroll
        for (int r = 0; r < ROWS; ++r)
#pragma unroll
            for (int c = 0; c < 8; ++c) acc[r][c] = fmaf(xv[r], wv[c], acc[r][c]);
    }

#pragma unroll
    for (int r = 0; r < ROWS; ++r) {
        int gr = row0 + r0 + r;
        if (gr >= n) continue;
        float di = dinv[gr];
        float* op = &outp[(size_t)gr * OC + c0];
        *(float4*)op = make_float4(acc[r][0] * di, acc[r][1] * di, acc[r][2] * di, acc[r][3] * di);
        *(float4*)(op + 4) = make_float4(acc[r][4] * di, acc[r][5] * di, acc[r][6] * di, acc[r][7] * di);
    }
}

// ---------------- fused decoder v2: 32 rows/block, transposed LDS h-tiles ----------------
// emb read from out[:,0:32); writes out[:,32:42) and out[:,42:170).
// LDS ~39 KB -> 4 blocks/CU (16 waves/CU). h stored transposed: xT[k][r].
__global__ __launch_bounds__(256, 4) void decoder_fused(
    const float* obuf,
    const float* __restrict__ Wp, const float* __restrict__ bp,
    const float* __restrict__ Wd1, const float* __restrict__ bd1,
    const float* __restrict__ Wd2, const float* __restrict__ bd2,
    const float* __restrict__ Wd3, const float* __restrict__ bd3,
    float* out, int n) {
    __shared__ float xAT[32][34];    // emb^T  [k][r]
    __shared__ float xBT[128][34];   // h1^T
    __shared__ float xCT[128][34];   // h2^T

    const int tid = threadIdx.x;
    const int row0 = blockIdx.x * 32;
    const int cg = tid & 15, rg = tid >> 4;   // 16 col-groups x 16 row-groups
    const int c0 = cg * 8, r0 = rg * 2;       // 8 cols x 2 rows per thread

    // ---- load emb tile transposed (float2 global reads; rows are 8B-aligned) ----
#pragma unroll
    for (int i = 0; i < 2; ++i) {
        int e = tid + i * 256;
        int r = e >> 4, q = e & 15;          // r in [0,32), q in [0,16)
        float2 v = make_float2(0.f, 0.f);
        if (row0 + r < n) v = *(const float2*)&obuf[(size_t)(row0 + r) * 170 + q * 2];
        xAT[q * 2][r] = v.x; xAT[q * 2 + 1][r] = v.y;
    }
    __syncthreads();

    // ---- head: out[:,32:42) = emb @ Wp + bp  (320 outputs) ----
    for (int e = tid; e < 320; e += 256) {
        int r = e / 10, c = e % 10;
        if (row0 + r < n) {
            float acc = bp[c];
#pragma unroll
            for (int k = 0; k < 32; ++k) acc = fmaf(xAT[k][r], Wp[k * 10 + c], acc);
            out[(size_t)(row0 + r) * 170 + 32 + c] = acc;
        }
    }

    // ---- stage 1: h1 = relu(emb @ Wd1 + bd1), K=32 -> xBT ----
    {
        float acc[2][8];
#pragma unroll
        for (int r = 0; r < 2; ++r)
#pragma unroll
            for (int c = 0; c < 8; ++c) acc[r][c] = bd1[c0 + c];
#pragma unroll 8
        for (int k = 0; k < 32; ++k) {
            float4 w0 = *(const float4*)&Wd1[k * 128 + c0];
            float4 w1 = *(const float4*)&Wd1[k * 128 + c0 + 4];
            float wv[8] = {w0.x, w0.y, w0.z, w0.w, w1.x, w1.y, w1.z, w1.w};
            float2 xv = *(const float2*)&xAT[k][r0];
#pragma unroll
            for (int c = 0; c < 8; ++c) {
                acc[0][c] = fmaf(xv.x, wv[c], acc[0][c]);
                acc[1][c] = fmaf(xv.y, wv[c], acc[1][c]);
            }
        }
#pragma unroll
        for (int c = 0; c < 8; ++c)
            *(float2*)&xBT[c0 + c][r0] = make_float2(fmaxf(acc[0][c], 0.f), fmaxf(acc[1][c], 0.f));
    }
    __syncthreads();

    // ---- stage 2: h2 = relu(h1 @ Wd2 + bd2), K=128 -> xCT ----
    {
        float acc[2][8];
#pragma unroll
        for (int r = 0; r < 2; ++r)
#pragma unroll
            for (int c = 0; c < 8; ++c) acc[r][c] = bd2[c0 + c];
#pragma unroll 8
        for (int k = 0; k < 128; ++k) {
            float4 w0 = *(const float4*)&Wd2[k * 128 + c0];
            float4 w1 = *(const float4*)&Wd2[k * 128 + c0 + 4];
            float wv[8] = {w0.x, w0.y, w0.z, w0.w, w1.x, w1.y, w1.z, w1.w};
            float2 xv = *(const float2*)&xBT[k][r0];
#pragma unroll
            for (int c = 0; c < 8; ++c) {
                acc[0][c] = fmaf(xv.x, wv[c], acc[0][c]);
                acc[1][c] = fmaf(xv.y, wv[c], acc[1][c]);
            }
        }
#pragma unroll
        for (int c = 0; c < 8; ++c)
            *(float2*)&xCT[c0 + c][r0] = make_float2(fmaxf(acc[0][c], 0.f), fmaxf(acc[1][c], 0.f));
    }
    __syncthreads();

    // ---- stage 3: dec = softplus(h2 @ Wd3 + bd3) -> out[:,42:170) ----
    {
        float acc[2][8];
#pragma unroll
        for (int r = 0; r < 2; ++r)
#pragma unroll
            for (int c = 0; c < 8; ++c) acc[r][c] = bd3[c0 + c];
#pragma unroll 8
        for (int k = 0; k < 128; ++k) {
            float4 w0 = *(const float4*)&Wd3[k * 128 + c0];
            float4 w1 = *(const float4*)&Wd3[k * 128 + c0 + 4];
            float wv[8] = {w0.x, w0.y, w0.z, w0.w, w1.x, w1.y, w1.z, w1.w};
            float2 xv = *(const float2*)&xCT[k][r0];
#pragma unroll
            for (int c = 0; c < 8; ++c) {
                acc[0][c] = fmaf(xv.x, wv[c], acc[0][c]);
                acc[1][c] = fmaf(xv.y, wv[c], acc[1][c]);
            }
        }
#pragma unroll
        for (int r = 0; r < 2; ++r) {
            int gr = row0 + r0 + r;
            if (gr >= n) continue;
            float* op = &out[(size_t)gr * 170 + 42 + c0];
#pragma unroll
            for (int c = 0; c < 8; c += 2) {
                float v0 = acc[r][c], v1 = acc[r][c + 1];
                v0 = fmaxf(v0, 0.f) + log1pf(expf(-fabsf(v0)));
                v1 = fmaxf(v1, 0.f) + log1pf(expf(-fabsf(v1)));
                *(float2*)(op + c) = make_float2(v0, v1);
            }
        }
    }
}

// ---------------- launch ----------------

extern "C" void kernel_launch(void* const* d_in, const int* in_sizes, int n_in,
                              void* d_out, int out_size, void* d_ws, size_t ws_size,
                              hipStream_t stream) {
    const float* raw_x = (const float*)d_in[0];
    const int*   ei    = (const int*)d_in[1];
    const float* W1 = (const float*)d_in[2];  const float* b1 = (const float*)d_in[3];
    const float* W2 = (const float*)d_in[4];  const float* b2 = (const float*)d_in[5];
    const float* Wp = (const float*)d_in[6];  const float* bp = (const float*)d_in[7];
    const float* Wd1 = (const float*)d_in[8]; const float* bd1 = (const float*)d_in[9];
    const float* Wd2 = (const float*)d_in[10]; const float* bd2 = (const float*)d_in[11];
    const float* Wd3 = (const float*)d_in[12]; const float* bd3 = (const float*)d_in[13];

    const int n = in_sizes[0] / 128;   // 50000
    const int E = in_sizes[1] / 2;     // 800000
    const int* row = ei;        // source
    const int* col = ei + E;    // target

    float* out = (float*)d_out;

    // workspace layout
    char* ws = (char*)d_ws;
    int*   deg    = (int*)ws;                        ws += (size_t)n * 4;
    float* dinv   = (float*)ws;                      ws += (size_t)n * 4;
    int*   rowptr = (int*)ws;                        ws += (size_t)(n + 4) * 4;
    int*   cursor = (int*)ws;                        ws += (size_t)n * 4;
    int*   bsum   = (int*)ws;                        ws += 64 * 4;
    int*   bpre   = (int*)ws;                        ws += 64 * 4;
    int*   csrc   = (int*)ws;                        ws += (size_t)E * 4;
    float* hs1    = (float*)ws;                      // [n,64]
    float* x1     = hs1 + (size_t)n * 64;            // [n,64]
    float* hs2    = x1 + (size_t)n * 64;             // [n,32]

    const int BS = 256;
    auto blocks = [](long long work, int bs) { return (unsigned)((work + bs - 1) / bs); };
    const int nb = (n + 1023) / 1024;                // scan blocks (49)

    // ---- graph structure (CSR by target) ----
    hipMemsetAsync(deg, 0, (size_t)n * 4, stream);
    deg_kernel<<<blocks(E, BS), BS, 0, stream>>>(col, deg, E);
    dinv_kernel<<<blocks(n, BS), BS, 0, stream>>>(deg, dinv, n);
    scan_phase1<<<nb, 256, 0, stream>>>(deg, bsum, n);
    scan_phase2<<<1, 64, 0, stream>>>(bsum, bpre, nb, rowptr, n, E);
    scan_phase3<<<nb, 256, 0, stream>>>(deg, bpre, rowptr, cursor, n);
    fill_kernel<<<blocks(E, BS), BS, 0, stream>>>(row, col, cursor, csrc, E);

    // ---- GCN layer 1: raw_x[128] -> 64 ----
    gemm_gcn<128, 64><<<blocks(n, 64), 256, 0, stream>>>(raw_x, W1, dinv, hs1, n);
    agg_finalize<64, true><<<blocks((long long)n * 16, BS), BS, 0, stream>>>(
        rowptr, csrc, hs1, dinv, b1, x1, n, 64, 0);

    // ---- GCN layer 2: x1[64] -> 32 ----
    gemm_gcn<64, 32><<<blocks(n, 64), 256, 0, stream>>>(x1, W2, dinv, hs2, n);
    agg_finalize<32, false><<<blocks((long long)n * 8, BS), BS, 0, stream>>>(
        rowptr, csrc, hs2, dinv, b2, out, n, 170, 0);   // emb -> out[:,0:32)

    // ---- fused decoder: head + 3 dense layers ----
    decoder_fused<<<blocks(n, 32), 256, 0, stream>>>(
        out, Wp, bp, Wd1, bd1, Wd2, bd2, Wd3, bd3, out, n);
}

// Round 6
// 332.036 us; speedup vs baseline: 1.1011x; 1.1011x over previous
//
#include <hip/hip_runtime.h>
#include <math.h>

// ---------------- degree / norm ----------------

__global__ void deg_kernel(const int* __restrict__ col, int* __restrict__ deg, int E) {
    int e = blockIdx.x * blockDim.x + threadIdx.x;
    if (e < E) atomicAdd(&deg[col[e]], 1);
}

__global__ void dinv_kernel(const int* __restrict__ deg, float* __restrict__ dinv, int n) {
    int i = blockIdx.x * blockDim.x + threadIdx.x;
    if (i < n) dinv[i] = 1.0f / sqrtf((float)(deg[i] + 1));  // +1 self loop
}

// ---------------- 3-phase scan: deg -> rowptr/cursor ----------------
__global__ void scan_phase1(const int* __restrict__ deg, int* __restrict__ bsum, int n) {
    __shared__ int red[256];
    int tid = threadIdx.x;
    int base = blockIdx.x * 1024 + tid * 4;
    int s = 0;
    if (base + 3 < n) { int4 v = *(const int4*)&deg[base]; s = v.x + v.y + v.z + v.w; }
    else { for (int i = 0; i < 4; ++i) if (base + i < n) s += deg[base + i]; }
    red[tid] = s; __syncthreads();
    for (int off = 128; off > 0; off >>= 1) { if (tid < off) red[tid] += red[tid + off]; __syncthreads(); }
    if (tid == 0) bsum[blockIdx.x] = red[0];
}

__global__ void scan_phase2(const int* __restrict__ bsum, int* __restrict__ bpre,
                            int nb, int* __restrict__ rowptr, int n, int E) {
    int tid = threadIdx.x;  // 64 threads
    int sv = (tid < nb) ? bsum[tid] : 0;
    int v = sv;
    for (int off = 1; off < 64; off <<= 1) {
        int w = __shfl_up(v, off);
        if (tid >= off) v += w;
    }
    if (tid < nb) bpre[tid] = v - sv;   // exclusive
    if (tid == 0) rowptr[n] = E;
}

__global__ void scan_phase3(const int* __restrict__ deg, const int* __restrict__ bpre,
                            int* __restrict__ rowptr, int* __restrict__ cursor, int n) {
    __shared__ int tsum[256];
    int tid = threadIdx.x;
    int base = blockIdx.x * 1024 + tid * 4;
    int d[4] = {0, 0, 0, 0};
    if (base + 3 < n) { int4 v = *(const int4*)&deg[base]; d[0] = v.x; d[1] = v.y; d[2] = v.z; d[3] = v.w; }
    else { for (int i = 0; i < 4; ++i) if (base + i < n) d[i] = deg[base + i]; }
    int s = d[0] + d[1] + d[2] + d[3];
    tsum[tid] = s; __syncthreads();
    for (int off = 1; off < 256; off <<= 1) {
        int v = tsum[tid];
        int w = (tid >= off) ? tsum[tid - off] : 0;
        __syncthreads();
        tsum[tid] = v + w;
        __syncthreads();
    }
    int pre = bpre[blockIdx.x] + tsum[tid] - s;
    for (int i = 0; i < 4; ++i) {
        int idx = base + i;
        if (idx < n) { rowptr[idx] = pre; cursor[idx] = pre; pre += d[i]; }
    }
}

__global__ void fill_kernel(const int* __restrict__ row, const int* __restrict__ col,
                            int* __restrict__ cursor, int* __restrict__ csrc, int E) {
    int e = blockIdx.x * blockDim.x + threadIdx.x;
    if (e < E) {
        int c = col[e];
        int slot = atomicAdd(&cursor[c], 1);
        csrc[slot] = row[e];
    }
}

// ---------------- CSR gather aggregation + finalize ----------------
template<int F, bool OV>
__global__ void agg_finalize(const int* __restrict__ rowptr, const int* __restrict__ csrc,
                             const float* __restrict__ hs, const float* __restrict__ dinv,
                             const float* __restrict__ b, float* __restrict__ out,
                             int n, int ostride, int col0) {
    constexpr int L = F / 4;                 // lanes per node
    int tid = blockIdx.x * blockDim.x + threadIdx.x;
    int node = tid / L, lane = tid % L;
    if (node >= n) return;
    int f0 = lane * 4;
    int beg = rowptr[node], end = rowptr[node + 1];
    float4 sum = make_float4(0.f, 0.f, 0.f, 0.f);
    for (int j = beg; j < end; ++j) {
        int s = csrc[j];                     // uniform across the L-lane group
        float4 v = *(const float4*)&hs[(size_t)s * F + f0];
        sum.x += v.x; sum.y += v.y; sum.z += v.z; sum.w += v.w;
    }
    float4 self = *(const float4*)&hs[(size_t)node * F + f0];
    float di = dinv[node];
    float r0 = fmaxf(di * (sum.x + self.x) + b[f0 + 0], 0.f);
    float r1 = fmaxf(di * (sum.y + self.y) + b[f0 + 1], 0.f);
    float r2 = fmaxf(di * (sum.z + self.z) + b[f0 + 2], 0.f);
    float r3 = fmaxf(di * (sum.w + self.w) + b[f0 + 3], 0.f);
    float* op = &out[(size_t)node * ostride + col0 + f0];
    if (OV) {
        *(float4*)op = make_float4(r0, r1, r2, r3);
    } else {
        op[0] = r0; op[1] = r1; op[2] = r2; op[3] = r3;
    }
}

// ---------------- GCN dense: out[r,c] = dinv[r] * sum_k x[r,k]*W[k,c] ----------------
template<int K, int OC>
__global__ __launch_bounds__(256) void gemm_gcn(
    const float* __restrict__ x, const float* __restrict__ W,
    const float* __restrict__ dinv, float* __restrict__ outp, int n) {
    constexpr int CG = OC / 8;        // col groups
    constexpr int RG = 256 / CG;      // row groups
    constexpr int ROWS = 64 / RG;     // rows per thread
    __shared__ float xL[64][K + 4];

    const int tid = threadIdx.x;
    const int cg = tid % CG, rg = tid / CG;
    const int c0 = cg * 8, r0 = rg * ROWS;
    const int row0 = blockIdx.x * 64;

#pragma unroll
    for (int i = 0; i < K / 16; ++i) {
        int e = tid + i * 256;
        int r = e / (K / 4), q = e % (K / 4);
        float4 v = make_float4(0.f, 0.f, 0.f, 0.f);
        if (row0 + r < n) v = *(const float4*)&x[(size_t)(row0 + r) * K + q * 4];
        *(float4*)&xL[r][q * 4] = v;
    }
    __syncthreads();

    float acc[ROWS][8];
#pragma unroll
    for (int r = 0; r < ROWS; ++r)
#pragma unroll
        for (int c = 0; c < 8; ++c) acc[r][c] = 0.f;

#pragma unroll 8
    for (int k = 0; k < K; ++k) {
        float4 w0 = *(const float4*)&W[(size_t)k * OC + c0];
        float4 w1 = *(const float4*)&W[(size_t)k * OC + c0 + 4];
        float wv[8] = {w0.x, w0.y, w0.z, w0.w, w1.x, w1.y, w1.z, w1.w};
        float xv[ROWS];
#pragma unroll
        for (int r = 0; r < ROWS; ++r) xv[r] = xL[r0 + r][k];
#pragma unroll
        for (int r = 0; r < ROWS; ++r)
#pragma unroll
            for (int c = 0; c < 8; ++c) acc[r][c] = fmaf(xv[r], wv[c], acc[r][c]);
    }

#pragma unroll
    for (int r = 0; r < ROWS; ++r) {
        int gr = row0 + r0 + r;
        if (gr >= n) continue;
        float di = dinv[gr];
        float* op = &outp[(size_t)gr * OC + c0];
        *(float4*)op = make_float4(acc[r][0] * di, acc[r][1] * di, acc[r][2] * di, acc[r][3] * di);
        *(float4*)(op + 4) = make_float4(acc[r][4] * di, acc[r][5] * di, acc[r][6] * di, acc[r][7] * di);
    }
}

// ---------------- fused decoder v3: 64 rows/block, ROWS=4/thread ----------------
// Per k: 2 vmem b128 (W) + 1 lds b128 (x, broadcast) + 32 FMA.
// One shared transposed h buffer reused for h1 and h2 (acc in regs across barrier).
// LDS = 8.7 + 34.8 = 43.5 KB -> 3 blocks/CU (12 waves/CU).
__global__ __launch_bounds__(256, 3) void decoder_fused(
    const float* obuf,
    const float* __restrict__ Wp, const float* __restrict__ bp,
    const float* __restrict__ Wd1, const float* __restrict__ bd1,
    const float* __restrict__ Wd2, const float* __restrict__ bd2,
    const float* __restrict__ Wd3, const float* __restrict__ bd3,
    float* out, int n) {
    __shared__ float eT[32][68];     // emb^T  [k][r], r in [0,64)
    __shared__ float hT[128][68];    // h1^T then h2^T

    const int tid = threadIdx.x;
    const int row0 = blockIdx.x * 64;
    const int cg = tid & 15, rg = tid >> 4;   // 16 col-groups x 16 row-groups
    const int c0 = cg * 8, r0 = rg * 4;       // 8 cols x 4 rows per thread

    // ---- load emb tile transposed (float2 global reads; rows 8B-aligned) ----
#pragma unroll
    for (int i = 0; i < 4; ++i) {
        int e = tid + i * 256;
        int r = e >> 4, q = e & 15;          // r in [0,64), q in [0,16)
        float2 v = make_float2(0.f, 0.f);
        if (row0 + r < n) v = *(const float2*)&obuf[(size_t)(row0 + r) * 170 + q * 2];
        eT[q * 2][r] = v.x; eT[q * 2 + 1][r] = v.y;
    }
    __syncthreads();

    // ---- head: out[:,32:42) = emb @ Wp + bp  (640 outputs) ----
    for (int e = tid; e < 640; e += 256) {
        int r = e / 10, c = e % 10;
        if (row0 + r < n) {
            float acc = bp[c];
#pragma unroll
            for (int k = 0; k < 32; ++k) acc = fmaf(eT[k][r], Wp[k * 10 + c], acc);
            out[(size_t)(row0 + r) * 170 + 32 + c] = acc;
        }
    }

    // ---- stage 1: h1 = relu(emb @ Wd1 + bd1), K=32 -> hT ----
    {
        float acc[4][8];
#pragma unroll
        for (int r = 0; r < 4; ++r)
#pragma unroll
            for (int c = 0; c < 8; ++c) acc[r][c] = bd1[c0 + c];
#pragma unroll 8
        for (int k = 0; k < 32; ++k) {
            float4 w0 = *(const float4*)&Wd1[k * 128 + c0];
            float4 w1 = *(const float4*)&Wd1[k * 128 + c0 + 4];
            float wv[8] = {w0.x, w0.y, w0.z, w0.w, w1.x, w1.y, w1.z, w1.w};
            float4 xv = *(const float4*)&eT[k][r0];
            float xa[4] = {xv.x, xv.y, xv.z, xv.w};
#pragma unroll
            for (int r = 0; r < 4; ++r)
#pragma unroll
                for (int c = 0; c < 8; ++c) acc[r][c] = fmaf(xa[r], wv[c], acc[r][c]);
        }
#pragma unroll
        for (int c = 0; c < 8; ++c)
            *(float4*)&hT[c0 + c][r0] = make_float4(fmaxf(acc[0][c], 0.f), fmaxf(acc[1][c], 0.f),
                                                    fmaxf(acc[2][c], 0.f), fmaxf(acc[3][c], 0.f));
    }
    __syncthreads();

    // ---- stage 2: h2 = relu(h1 @ Wd2 + bd2), K=128; overwrite hT after barrier ----
    {
        float acc[4][8];
#pragma unroll
        for (int r = 0; r < 4; ++r)
#pragma unroll
            for (int c = 0; c < 8; ++c) acc[r][c] = bd2[c0 + c];
#pragma unroll 8
        for (int k = 0; k < 128; ++k) {
            float4 w0 = *(const float4*)&Wd2[k * 128 + c0];
            float4 w1 = *(const float4*)&Wd2[k * 128 + c0 + 4];
            float wv[8] = {w0.x, w0.y, w0.z, w0.w, w1.x, w1.y, w1.z, w1.w};
            float4 xv = *(const float4*)&hT[k][r0];
            float xa[4] = {xv.x, xv.y, xv.z, xv.w};
#pragma unroll
            for (int r = 0; r < 4; ++r)
#pragma unroll
                for (int c = 0; c < 8; ++c) acc[r][c] = fmaf(xa[r], wv[c], acc[r][c]);
        }
        __syncthreads();   // all reads of h1 done
#pragma unroll
        for (int c = 0; c < 8; ++c)
            *(float4*)&hT[c0 + c][r0] = make_float4(fmaxf(acc[0][c], 0.f), fmaxf(acc[1][c], 0.f),
                                                    fmaxf(acc[2][c], 0.f), fmaxf(acc[3][c], 0.f));
    }
    __syncthreads();

    // ---- stage 3: dec = softplus(h2 @ Wd3 + bd3) -> out[:,42:170) ----
    {
        float acc[4][8];
#pragma unroll
        for (int r = 0; r < 4; ++r)
#pragma unroll
            for (int c = 0; c < 8; ++c) acc[r][c] = bd3[c0 + c];
#pragma unroll 8
        for (int k = 0; k < 128; ++k) {
            float4 w0 = *(const float4*)&Wd3[k * 128 + c0];
            float4 w1 = *(const float4*)&Wd3[k * 128 + c0 + 4];
            float wv[8] = {w0.x, w0.y, w0.z, w0.w, w1.x, w1.y, w1.z, w1.w};
            float4 xv = *(const float4*)&hT[k][r0];
            float xa[4] = {xv.x, xv.y, xv.z, xv.w};
#pragma unroll
            for (int r = 0; r < 4; ++r)
#pragma unroll
                for (int c = 0; c < 8; ++c) acc[r][c] = fmaf(xa[r], wv[c], acc[r][c]);
        }
#pragma unroll
        for (int r = 0; r < 4; ++r) {
            int gr = row0 + r0 + r;
            if (gr >= n) continue;
            float* op = &out[(size_t)gr * 170 + 42 + c0];
#pragma unroll
            for (int c = 0; c < 8; c += 2) {
                float v0 = acc[r][c], v1 = acc[r][c + 1];
                v0 = fmaxf(v0, 0.f) + log1pf(expf(-fabsf(v0)));
                v1 = fmaxf(v1, 0.f) + log1pf(expf(-fabsf(v1)));
                *(float2*)(op + c) = make_float2(v0, v1);
            }
        }
    }
}

// ---------------- launch ----------------

extern "C" void kernel_launch(void* const* d_in, const int* in_sizes, int n_in,
                              void* d_out, int out_size, void* d_ws, size_t ws_size,
                              hipStream_t stream) {
    const float* raw_x = (const float*)d_in[0];
    const int*   ei    = (const int*)d_in[1];
    const float* W1 = (const float*)d_in[2];  const float* b1 = (const float*)d_in[3];
    const float* W2 = (const float*)d_in[4];  const float* b2 = (const float*)d_in[5];
    const float* Wp = (const float*)d_in[6];  const float* bp = (const float*)d_in[7];
    const float* Wd1 = (const float*)d_in[8]; const float* bd1 = (const float*)d_in[9];
    const float* Wd2 = (const float*)d_in[10]; const float* bd2 = (const float*)d_in[11];
    const float* Wd3 = (const float*)d_in[12]; const float* bd3 = (const float*)d_in[13];

    const int n = in_sizes[0] / 128;   // 50000
    const int E = in_sizes[1] / 2;     // 800000
    const int* row = ei;        // source
    const int* col = ei + E;    // target

    float* out = (float*)d_out;

    // workspace layout
    char* ws = (char*)d_ws;
    int*   deg    = (int*)ws;                        ws += (size_t)n * 4;
    float* dinv   = (float*)ws;                      ws += (size_t)n * 4;
    int*   rowptr = (int*)ws;                        ws += (size_t)(n + 4) * 4;
    int*   cursor = (int*)ws;                        ws += (size_t)n * 4;
    int*   bsum   = (int*)ws;                        ws += 64 * 4;
    int*   bpre   = (int*)ws;                        ws += 64 * 4;
    int*   csrc   = (int*)ws;                        ws += (size_t)E * 4;
    float* hs1    = (float*)ws;                      // [n,64]
    float* x1     = hs1 + (size_t)n * 64;            // [n,64]
    float* hs2    = x1 + (size_t)n * 64;             // [n,32]

    const int BS = 256;
    auto blocks = [](long long work, int bs) { return (unsigned)((work + bs - 1) / bs); };
    const int nb = (n + 1023) / 1024;                // scan blocks (49)

    // ---- graph structure (CSR by target) ----
    hipMemsetAsync(deg, 0, (size_t)n * 4, stream);
    deg_kernel<<<blocks(E, BS), BS, 0, stream>>>(col, deg, E);
    dinv_kernel<<<blocks(n, BS), BS, 0, stream>>>(deg, dinv, n);
    scan_phase1<<<nb, 256, 0, stream>>>(deg, bsum, n);
    scan_phase2<<<1, 64, 0, stream>>>(bsum, bpre, nb, rowptr, n, E);
    scan_phase3<<<nb, 256, 0, stream>>>(deg, bpre, rowptr, cursor, n);
    fill_kernel<<<blocks(E, BS), BS, 0, stream>>>(row, col, cursor, csrc, E);

    // ---- GCN layer 1: raw_x[128] -> 64 ----
    gemm_gcn<128, 64><<<blocks(n, 64), 256, 0, stream>>>(raw_x, W1, dinv, hs1, n);
    agg_finalize<64, true><<<blocks((long long)n * 16, BS), BS, 0, stream>>>(
        rowptr, csrc, hs1, dinv, b1, x1, n, 64, 0);

    // ---- GCN layer 2: x1[64] -> 32 ----
    gemm_gcn<64, 32><<<blocks(n, 64), 256, 0, stream>>>(x1, W2, dinv, hs2, n);
    agg_finalize<32, false><<<blocks((long long)n * 8, BS), BS, 0, stream>>>(
        rowptr, csrc, hs2, dinv, b2, out, n, 170, 0);   // emb -> out[:,0:32)

    // ---- fused decoder: head + 3 dense layers ----
    decoder_fused<<<blocks(n, 64), 256, 0, stream>>>(
        out, Wp, bp, Wd1, bd1, Wd2, bd2, Wd3, bd3, out, n);
}

// Round 7
// 304.541 us; speedup vs baseline: 1.2005x; 1.0903x over previous
//
#include <hip/hip_runtime.h>
#include <math.h>

typedef unsigned short u16;
typedef unsigned int u32;
typedef __attribute__((ext_vector_type(8))) short bf8;   // 8 bf16 = 4 VGPR
typedef __attribute__((ext_vector_type(4))) float f4;    // 4 f32 acc

__device__ __forceinline__ u16 bfhi(float x) {
    u32 u = __float_as_uint(x);
    u32 r = u + 0x7FFFu + ((u >> 16) & 1u);   // RNE
    return (u16)(r >> 16);
}
__device__ __forceinline__ float bf2f(u16 h) { return __uint_as_float(((u32)h) << 16); }

// ---------------- degree / norm ----------------

__global__ void deg_kernel(const int* __restrict__ col, int* __restrict__ deg, int E) {
    int e = blockIdx.x * blockDim.x + threadIdx.x;
    if (e < E) atomicAdd(&deg[col[e]], 1);
}

__global__ void dinv_kernel(const int* __restrict__ deg, float* __restrict__ dinv, int n) {
    int i = blockIdx.x * blockDim.x + threadIdx.x;
    if (i < n) dinv[i] = 1.0f / sqrtf((float)(deg[i] + 1));  // +1 self loop
}

// ---------------- 3-phase scan: deg -> rowptr/cursor ----------------
__global__ void scan_phase1(const int* __restrict__ deg, int* __restrict__ bsum, int n) {
    __shared__ int red[256];
    int tid = threadIdx.x;
    int base = blockIdx.x * 1024 + tid * 4;
    int s = 0;
    if (base + 3 < n) { int4 v = *(const int4*)&deg[base]; s = v.x + v.y + v.z + v.w; }
    else { for (int i = 0; i < 4; ++i) if (base + i < n) s += deg[base + i]; }
    red[tid] = s; __syncthreads();
    for (int off = 128; off > 0; off >>= 1) { if (tid < off) red[tid] += red[tid + off]; __syncthreads(); }
    if (tid == 0) bsum[blockIdx.x] = red[0];
}

__global__ void scan_phase2(const int* __restrict__ bsum, int* __restrict__ bpre,
                            int nb, int* __restrict__ rowptr, int n, int E) {
    int tid = threadIdx.x;  // 64 threads
    int sv = (tid < nb) ? bsum[tid] : 0;
    int v = sv;
    for (int off = 1; off < 64; off <<= 1) {
        int w = __shfl_up(v, off);
        if (tid >= off) v += w;
    }
    if (tid < nb) bpre[tid] = v - sv;   // exclusive
    if (tid == 0) rowptr[n] = E;
}

__global__ void scan_phase3(const int* __restrict__ deg, const int* __restrict__ bpre,
                            int* __restrict__ rowptr, int* __restrict__ cursor, int n) {
    __shared__ int tsum[256];
    int tid = threadIdx.x;
    int base = blockIdx.x * 1024 + tid * 4;
    int d[4] = {0, 0, 0, 0};
    if (base + 3 < n) { int4 v = *(const int4*)&deg[base]; d[0] = v.x; d[1] = v.y; d[2] = v.z; d[3] = v.w; }
    else { for (int i = 0; i < 4; ++i) if (base + i < n) d[i] = deg[base + i]; }
    int s = d[0] + d[1] + d[2] + d[3];
    tsum[tid] = s; __syncthreads();
    for (int off = 1; off < 256; off <<= 1) {
        int v = tsum[tid];
        int w = (tid >= off) ? tsum[tid - off] : 0;
        __syncthreads();
        tsum[tid] = v + w;
        __syncthreads();
    }
    int pre = bpre[blockIdx.x] + tsum[tid] - s;
    for (int i = 0; i < 4; ++i) {
        int idx = base + i;
        if (idx < n) { rowptr[idx] = pre; cursor[idx] = pre; pre += d[i]; }
    }
}

__global__ void fill_kernel(const int* __restrict__ row, const int* __restrict__ col,
                            int* __restrict__ cursor, int* __restrict__ csrc, int E) {
    int e = blockIdx.x * blockDim.x + threadIdx.x;
    if (e < E) {
        int c = col[e];
        int slot = atomicAdd(&cursor[c], 1);
        csrc[slot] = row[e];
    }
}

// ---------------- CSR gather aggregation + finalize ----------------
template<int F, bool OV>
__global__ void agg_finalize(const int* __restrict__ rowptr, const int* __restrict__ csrc,
                             const float* __restrict__ hs, const float* __restrict__ dinv,
                             const float* __restrict__ b, float* __restrict__ out,
                             int n, int ostride, int col0) {
    constexpr int L = F / 4;                 // lanes per node
    int tid = blockIdx.x * blockDim.x + threadIdx.x;
    int node = tid / L, lane = tid % L;
    if (node >= n) return;
    int f0 = lane * 4;
    int beg = rowptr[node], end = rowptr[node + 1];
    float4 sum = make_float4(0.f, 0.f, 0.f, 0.f);
    for (int j = beg; j < end; ++j) {
        int s = csrc[j];                     // uniform across the L-lane group
        float4 v = *(const float4*)&hs[(size_t)s * F + f0];
        sum.x += v.x; sum.y += v.y; sum.z += v.z; sum.w += v.w;
    }
    float4 self = *(const float4*)&hs[(size_t)node * F + f0];
    float di = dinv[node];
    float r0 = fmaxf(di * (sum.x + self.x) + b[f0 + 0], 0.f);
    float r1 = fmaxf(di * (sum.y + self.y) + b[f0 + 1], 0.f);
    float r2 = fmaxf(di * (sum.z + self.z) + b[f0 + 2], 0.f);
    float r3 = fmaxf(di * (sum.w + self.w) + b[f0 + 3], 0.f);
    float* op = &out[(size_t)node * ostride + col0 + f0];
    if (OV) {
        *(float4*)op = make_float4(r0, r1, r2, r3);
    } else {
        op[0] = r0; op[1] = r1; op[2] = r2; op[3] = r3;
    }
}

// ---------------- GCN dense: out[r,c] = dinv[r] * sum_k x[r,k]*W[k,c] ----------------
template<int K, int OC>
__global__ __launch_bounds__(256) void gemm_gcn(
    const float* __restrict__ x, const float* __restrict__ W,
    const float* __restrict__ dinv, float* __restrict__ outp, int n) {
    constexpr int CG = OC / 8;        // col groups
    constexpr int RG = 256 / CG;      // row groups
    constexpr int ROWS = 64 / RG;     // rows per thread
    __shared__ float xL[64][K + 4];

    const int tid = threadIdx.x;
    const int cg = tid % CG, rg = tid / CG;
    const int c0 = cg * 8, r0 = rg * ROWS;
    const int row0 = blockIdx.x * 64;

#pragma unroll
    for (int i = 0; i < K / 16; ++i) {
        int e = tid + i * 256;
        int r = e / (K / 4), q = e % (K / 4);
        float4 v = make_float4(0.f, 0.f, 0.f, 0.f);
        if (row0 + r < n) v = *(const float4*)&x[(size_t)(row0 + r) * K + q * 4];
        *(float4*)&xL[r][q * 4] = v;
    }
    __syncthreads();

    float acc[ROWS][8];
#pragma unroll
    for (int r = 0; r < ROWS; ++r)
#pragma unroll
        for (int c = 0; c < 8; ++c) acc[r][c] = 0.f;

#pragma unroll 8
    for (int k = 0; k < K; ++k) {
        float4 w0 = *(const float4*)&W[(size_t)k * OC + c0];
        float4 w1 = *(const float4*)&W[(size_t)k * OC + c0 + 4];
        float wv[8] = {w0.x, w0.y, w0.z, w0.w, w1.x, w1.y, w1.z, w1.w};
        float xv[ROWS];
#pragma unroll
        for (int r = 0; r < ROWS; ++r) xv[r] = xL[r0 + r][k];
#pragma unroll
        for (int r = 0; r < ROWS; ++r)
#pragma unroll
            for (int c = 0; c < 8; ++c) acc[r][c] = fmaf(xv[r], wv[c], acc[r][c]);
    }

#pragma unroll
    for (int r = 0; r < ROWS; ++r) {
        int gr = row0 + r0 + r;
        if (gr >= n) continue;
        float di = dinv[gr];
        float* op = &outp[(size_t)gr * OC + c0];
        *(float4*)op = make_float4(acc[r][0] * di, acc[r][1] * di, acc[r][2] * di, acc[r][3] * di);
        *(float4*)(op + 4) = make_float4(acc[r][4] * di, acc[r][5] * di, acc[r][6] * di, acc[r][7] * di);
    }
}

// ---------------- weight pre-swizzle into MFMA B-fragment order ----------------
// B-frag for mfma_f32_16x16x32_bf16: lane l holds B[kt*32 + (l>>4)*8 + j][ct*16 + (l&15)], j=0..7
// tiles: 0..7 Wd1(32x128), 8..39 Wd2(128x128), 40..71 Wd3(128x128), 72 Wp(32x10 pad16)
__global__ void wswz_kernel(const float* __restrict__ Wd1, const float* __restrict__ Wd2,
                            const float* __restrict__ Wd3, const float* __restrict__ Wp,
                            u16* __restrict__ whi, u16* __restrict__ wlo) {
    int t = blockIdx.x, l = threadIdx.x;   // 73 blocks x 64 threads
    const float* W; int C, kt, ct;
    if (t < 8)       { W = Wd1; C = 128; kt = 0;           ct = t; }
    else if (t < 40) { W = Wd2; C = 128; kt = (t - 8) >> 3; ct = (t - 8) & 7; }
    else if (t < 72) { W = Wd3; C = 128; kt = (t - 40) >> 3; ct = (t - 40) & 7; }
    else             { W = Wp;  C = 10;  kt = 0;           ct = 0; }
    int kbase = kt * 32 + (l >> 4) * 8;
    int c = ct * 16 + (l & 15);
    size_t base = (size_t)t * 512 + (size_t)l * 8;
#pragma unroll
    for (int j = 0; j < 8; ++j) {
        float v = (c < C) ? W[(size_t)(kbase + j) * C + c] : 0.f;
        u16 h = bfhi(v);
        whi[base + j] = (u16)h;
        wlo[base + j] = bfhi(v - bf2f(h));
    }
}

// ---------------- MFMA fused decoder ----------------
// 64 rows/block, 4 waves; wave w owns rows [w*16, w*16+16) x all 128 cols.
// Split-bf16: x*w ~= xh*wh + xl*wh + xh*wl  (3 MFMAs per tile).
// h1/h2 as bf16 hi/lo planes in LDS. A-frag = 1 ds_read_b128.
__global__ __launch_bounds__(256) void decoder_mfma(
    const float* __restrict__ obuf,
    const u16* __restrict__ whi, const u16* __restrict__ wlo,
    const float* __restrict__ bp, const float* __restrict__ bd1,
    const float* __restrict__ bd2, const float* __restrict__ bd3,
    float* __restrict__ out, int n) {
    __shared__ u16 eH[64][40], eL[64][40];     // emb planes  (stride 80B, 16B-aligned)
    __shared__ u16 hH[64][136], hL[64][136];   // h planes    (stride 272B, 16B-aligned)

    const int tid = threadIdx.x;
    const int l = tid & 63, wv = tid >> 6;     // lane, wave strip
    const int lr = l & 15, lg = l >> 4;        // frag row/col idx, k-group
    const int row0 = blockIdx.x * 64;

    // ---- load emb (64 x 32 f32) -> split bf16 planes ----
    {
        int r = tid >> 2, q = (tid & 3) * 8;
        const float* src = &obuf[(size_t)(row0 + r) * 170 + q];
        bool ok = (row0 + r) < n;
#pragma unroll
        for (int i = 0; i < 8; i += 2) {
            float2 v = ok ? *(const float2*)(src + i) : make_float2(0.f, 0.f);
            u16 h0 = bfhi(v.x), h1 = bfhi(v.y);
            u16 l0 = bfhi(v.x - bf2f(h0)), l1 = bfhi(v.y - bf2f(h1));
            *(u32*)&eH[r][q + i] = (u32)h0 | ((u32)h1 << 16);
            *(u32*)&eL[r][q + i] = (u32)l0 | ((u32)l1 << 16);
        }
    }
    __syncthreads();

    f4 acc[8];
    // ---- stage 1: h1 = relu(emb @ Wd1 + bd1)  (K=32, 1 k-step) + head ----
    {
#pragma unroll
        for (int ct = 0; ct < 8; ++ct) acc[ct] = (f4){0.f, 0.f, 0.f, 0.f};
        f4 accp = (f4){0.f, 0.f, 0.f, 0.f};
        bf8 aH = *(const bf8*)&eH[wv * 16 + lr][lg * 8];
        bf8 aL = *(const bf8*)&eL[wv * 16 + lr][lg * 8];
#pragma unroll
        for (int ct = 0; ct < 8; ++ct) {
            size_t tb = (size_t)ct * 512 + (size_t)l * 8;
            bf8 bH = *(const bf8*)(whi + tb);
            bf8 bL = *(const bf8*)(wlo + tb);
            acc[ct] = __builtin_amdgcn_mfma_f32_16x16x32_bf16(aH, bH, acc[ct], 0, 0, 0);
            acc[ct] = __builtin_amdgcn_mfma_f32_16x16x32_bf16(aL, bH, acc[ct], 0, 0, 0);
            acc[ct] = __builtin_amdgcn_mfma_f32_16x16x32_bf16(aH, bL, acc[ct], 0, 0, 0);
        }
        {   // head: tile 72 (Wp padded to 16 cols)
            size_t tb = (size_t)72 * 512 + (size_t)l * 8;
            bf8 pH = *(const bf8*)(whi + tb);
            bf8 pL = *(const bf8*)(wlo + tb);
            accp = __builtin_amdgcn_mfma_f32_16x16x32_bf16(aH, pH, accp, 0, 0, 0);
            accp = __builtin_amdgcn_mfma_f32_16x16x32_bf16(aL, pH, accp, 0, 0, 0);
            accp = __builtin_amdgcn_mfma_f32_16x16x32_bf16(aH, pL, accp, 0, 0, 0);
            if (lr < 10) {
                float bpv = bp[lr];
#pragma unroll
                for (int rg = 0; rg < 4; ++rg) {
                    int grow = row0 + wv * 16 + lg * 4 + rg;
                    if (grow < n) out[(size_t)grow * 170 + 32 + lr] = accp[rg] + bpv;
                }
            }
        }
#pragma unroll
        for (int ct = 0; ct < 8; ++ct) {
            float bv = bd1[ct * 16 + lr];
#pragma unroll
            for (int rg = 0; rg < 4; ++rg) {
                float v = fmaxf(acc[ct][rg] + bv, 0.f);
                u16 vh = bfhi(v), vl = bfhi(v - bf2f(vh));
                int rr = wv * 16 + lg * 4 + rg, cc = ct * 16 + lr;
                hH[rr][cc] = vh; hL[rr][cc] = vl;
            }
        }
    }
    __syncthreads();

    // ---- stage 2: h2 = relu(h1 @ Wd2 + bd2)  (K=128) ----
    {
#pragma unroll
        for (int ct = 0; ct < 8; ++ct) acc[ct] = (f4){0.f, 0.f, 0.f, 0.f};
#pragma unroll
        for (int kt = 0; kt < 4; ++kt) {
            bf8 aH = *(const bf8*)&hH[wv * 16 + lr][kt * 32 + lg * 8];
            bf8 aL = *(const bf8*)&hL[wv * 16 + lr][kt * 32 + lg * 8];
#pragma unroll
            for (int ct = 0; ct < 8; ++ct) {
                size_t tb = (size_t)(8 + kt * 8 + ct) * 512 + (size_t)l * 8;
                bf8 bH = *(const bf8*)(whi + tb);
                bf8 bL = *(const bf8*)(wlo + tb);
                acc[ct] = __builtin_amdgcn_mfma_f32_16x16x32_bf16(aH, bH, acc[ct], 0, 0, 0);
                acc[ct] = __builtin_amdgcn_mfma_f32_16x16x32_bf16(aL, bH, acc[ct], 0, 0, 0);
                acc[ct] = __builtin_amdgcn_mfma_f32_16x16x32_bf16(aH, bL, acc[ct], 0, 0, 0);
            }
        }
        __syncthreads();   // all reads of h1 done
#pragma unroll
        for (int ct = 0; ct < 8; ++ct) {
            float bv = bd2[ct * 16 + lr];
#pragma unroll
            for (int rg = 0; rg < 4; ++rg) {
                float v = fmaxf(acc[ct][rg] + bv, 0.f);
                u16 vh = bfhi(v), vl = bfhi(v - bf2f(vh));
                int rr = wv * 16 + lg * 4 + rg, cc = ct * 16 + lr;
                hH[rr][cc] = vh; hL[rr][cc] = vl;
            }
        }
    }
    __syncthreads();

    // ---- stage 3: dec = softplus(h2 @ Wd3 + bd3) -> out[:,42:170) ----
    {
#pragma unroll
        for (int ct = 0; ct < 8; ++ct) acc[ct] = (f4){0.f, 0.f, 0.f, 0.f};
#pragma unroll
        for (int kt = 0; kt < 4; ++kt) {
            bf8 aH = *(const bf8*)&hH[wv * 16 + lr][kt * 32 + lg * 8];
            bf8 aL = *(const bf8*)&hL[wv * 16 + lr][kt * 32 + lg * 8];
#pragma unroll
            for (int ct = 0; ct < 8; ++ct) {
                size_t tb = (size_t)(40 + kt * 8 + ct) * 512 + (size_t)l * 8;
                bf8 bH = *(const bf8*)(whi + tb);
                bf8 bL = *(const bf8*)(wlo + tb);
                acc[ct] = __builtin_amdgcn_mfma_f32_16x16x32_bf16(aH, bH, acc[ct], 0, 0, 0);
                acc[ct] = __builtin_amdgcn_mfma_f32_16x16x32_bf16(aL, bH, acc[ct], 0, 0, 0);
                acc[ct] = __builtin_amdgcn_mfma_f32_16x16x32_bf16(aH, bL, acc[ct], 0, 0, 0);
            }
        }
#pragma unroll
        for (int ct = 0; ct < 8; ++ct) {
            float bv = bd3[ct * 16 + lr];
#pragma unroll
            for (int rg = 0; rg < 4; ++rg) {
                int grow = row0 + wv * 16 + lg * 4 + rg;
                if (grow < n) {
                    float v = acc[ct][rg] + bv;
                    v = fmaxf(v, 0.f) + log1pf(expf(-fabsf(v)));
                    out[(size_t)grow * 170 + 42 + ct * 16 + lr] = v;
                }
            }
        }
    }
}

// ---------------- launch ----------------

extern "C" void kernel_launch(void* const* d_in, const int* in_sizes, int n_in,
                              void* d_out, int out_size, void* d_ws, size_t ws_size,
                              hipStream_t stream) {
    const float* raw_x = (const float*)d_in[0];
    const int*   ei    = (const int*)d_in[1];
    const float* W1 = (const float*)d_in[2];  const float* b1 = (const float*)d_in[3];
    const float* W2 = (const float*)d_in[4];  const float* b2 = (const float*)d_in[5];
    const float* Wp = (const float*)d_in[6];  const float* bp = (const float*)d_in[7];
    const float* Wd1 = (const float*)d_in[8]; const float* bd1 = (const float*)d_in[9];
    const float* Wd2 = (const float*)d_in[10]; const float* bd2 = (const float*)d_in[11];
    const float* Wd3 = (const float*)d_in[12]; const float* bd3 = (const float*)d_in[13];

    const int n = in_sizes[0] / 128;   // 50000
    const int E = in_sizes[1] / 2;     // 800000
    const int* row = ei;        // source
    const int* col = ei + E;    // target

    float* out = (float*)d_out;

    // workspace layout
    char* ws = (char*)d_ws;
    int*   deg    = (int*)ws;                        ws += (size_t)n * 4;
    float* dinv   = (float*)ws;                      ws += (size_t)n * 4;
    int*   rowptr = (int*)ws;                        ws += (size_t)(n + 4) * 4;
    int*   cursor = (int*)ws;                        ws += (size_t)n * 4;
    int*   bsum   = (int*)ws;                        ws += 64 * 4;
    int*   bpre   = (int*)ws;                        ws += 64 * 4;
    int*   csrc   = (int*)ws;                        ws += (size_t)E * 4;
    float* hs1    = (float*)ws;                      // [n,64]
    float* x1     = hs1 + (size_t)n * 64;            // [n,64]
    float* hs2    = x1 + (size_t)n * 64;             // [n,32]
    u16*   wswHi  = (u16*)(hs2 + (size_t)n * 32);    // 73*512 u16
    u16*   wswLo  = wswHi + 73 * 512;

    const int BS = 256;
    auto blocks = [](long long work, int bs) { return (unsigned)((work + bs - 1) / bs); };
    const int nb = (n + 1023) / 1024;                // scan blocks (49)

    // ---- graph structure (CSR by target) + weight swizzle ----
    hipMemsetAsync(deg, 0, (size_t)n * 4, stream);
    wswz_kernel<<<73, 64, 0, stream>>>(Wd1, Wd2, Wd3, Wp, wswHi, wswLo);
    deg_kernel<<<blocks(E, BS), BS, 0, stream>>>(col, deg, E);
    dinv_kernel<<<blocks(n, BS), BS, 0, stream>>>(deg, dinv, n);
    scan_phase1<<<nb, 256, 0, stream>>>(deg, bsum, n);
    scan_phase2<<<1, 64, 0, stream>>>(bsum, bpre, nb, rowptr, n, E);
    scan_phase3<<<nb, 256, 0, stream>>>(deg, bpre, rowptr, cursor, n);
    fill_kernel<<<blocks(E, BS), BS, 0, stream>>>(row, col, cursor, csrc, E);

    // ---- GCN layer 1: raw_x[128] -> 64 ----
    gemm_gcn<128, 64><<<blocks(n, 64), 256, 0, stream>>>(raw_x, W1, dinv, hs1, n);
    agg_finalize<64, true><<<blocks((long long)n * 16, BS), BS, 0, stream>>>(
        rowptr, csrc, hs1, dinv, b1, x1, n, 64, 0);

    // ---- GCN layer 2: x1[64] -> 32 ----
    gemm_gcn<64, 32><<<blocks(n, 64), 256, 0, stream>>>(x1, W2, dinv, hs2, n);
    agg_finalize<32, false><<<blocks((long long)n * 8, BS), BS, 0, stream>>>(
        rowptr, csrc, hs2, dinv, b2, out, n, 170, 0);   // emb -> out[:,0:32)

    // ---- fused MFMA decoder: head + 3 dense layers ----
    decoder_mfma<<<blocks(n, 64), 256, 0, stream>>>(
        out, wswHi, wswLo, bp, bd1, bd2, bd3, out, n);
}